// Round 14
// baseline (150.300 us; speedup 1.0000x reference)
//
#include <hip/hip_runtime.h>
#include <hip/hip_bf16.h>

typedef __hip_bfloat16 bf16;
typedef __attribute__((ext_vector_type(8))) short short8;   // 8 bf16 = 4 VGPRs
typedef __attribute__((ext_vector_type(4))) float f32x4;    // MFMA C/D frag

__device__ __forceinline__ short8 ld8(const void* p) { return *(const short8*)p; }

// async global->LDS, 16B per lane: LDS dest = (wave-uniform) base + lane*16
__device__ __forceinline__ void async_cp16(bf16* lds, const bf16* g) {
    __builtin_amdgcn_global_load_lds(
        (const __attribute__((address_space(1))) unsigned int*)g,
        (__attribute__((address_space(3))) unsigned int*)lds, 16, 0, 0);
}

struct bf4 { bf16 a, b, c, d; };

// ---------------------------------------------------------------------------
__global__ void cast_kernel(const float* __restrict__ s0, bf16* __restrict__ d0, int n0_,
                            const float* __restrict__ s1, bf16* __restrict__ d1, int n1_,
                            const float* __restrict__ s2, bf16* __restrict__ d2, int n2_,
                            const float* __restrict__ s3, bf16* __restrict__ d3, int n3_,
                            const float* __restrict__ s4, bf16* __restrict__ d4, int n4_) {
    const float* srcs[5] = {s0, s1, s2, s3, s4};
    bf16* dsts[5] = {d0, d1, d2, d3, d4};
    int ns[5] = {n0_, n1_, n2_, n3_, n4_};
    int stride = gridDim.x * blockDim.x;
    int t0 = blockIdx.x * blockDim.x + threadIdx.x;
#pragma unroll
    for (int a = 0; a < 5; ++a) {
        const float4* src = (const float4*)srcs[a];
        bf4* dst = (bf4*)dsts[a];
        int n4 = ns[a] >> 2;
        for (int i = t0; i < n4; i += stride) {
            float4 v = src[i];
            bf4 o = {__float2bfloat16(v.x), __float2bfloat16(v.y),
                     __float2bfloat16(v.z), __float2bfloat16(v.w)};
            dst[i] = o;
        }
    }
}

// ---------------------------------------------------------------------------
// 2-wave GEMM staging into XOR-16 swizzled LDS. Unit t covers rows 4t..4t+3
// (lane -> row 4t + (lane>>4), slot chunk lane&15, src chunk (lane&15)^(row&15)).
// A-tile 32x128 (8 units), B-tile 64x128 (16 units); 12 units per wave.
#define STAGE_A32(dst, src_base, row0, ldk)                                    \
    _Pragma("unroll")                                                          \
    for (int u = 0; u < 4; ++u) {                                              \
        int t = wave * 4 + u;                                                  \
        int row = t * 4 + (lane >> 4);                                         \
        int gsrc = (lane & 15) ^ (row & 15);                                   \
        async_cp16(&dst[t * 4][0], src_base + (size_t)(row0 + row) * ldk + k0 + gsrc * 8); \
    }
#define STAGE_B64(dst, src_base, row0, ldk)                                    \
    _Pragma("unroll")                                                          \
    for (int u = 0; u < 8; ++u) {                                              \
        int t = wave * 8 + u;                                                  \
        int row = t * 4 + (lane >> 4);                                         \
        int gsrc = (lane & 15) ^ (row & 15);                                   \
        async_cp16(&dst[t * 4][0], src_base + (size_t)(row0 + row) * ldk + k0 + gsrc * 8); \
    }

// ---------------------------------------------------------------------------
// Fused Q/K/V projection. A = hsb [M,K]. N-tiles: 0..15 -> Q (scaled 1/8),
// 16 -> K, 17 -> V (stored transposed). 32(M)x64(N) tile, BK=128, 128 thr.
__global__ void qkv_proj_kernel(const bf16* __restrict__ A,
                                const bf16* __restrict__ Wq, const bf16* __restrict__ Wk,
                                const bf16* __restrict__ Wv,
                                const float* __restrict__ bq, const float* __restrict__ bk,
                                const float* __restrict__ bv,
                                bf16* __restrict__ qo, bf16* __restrict__ ko,
                                bf16* __restrict__ vto, int M, int K) {
    __shared__ __align__(16) bf16 As[32][128]; // 8 KB
    __shared__ __align__(16) bf16 Bs[64][128]; // 16 KB
    const int nt = blockIdx.x;
    const bf16* W;
    const float* bias;
    int mode, nw0;
    if (nt < 16)      { W = Wq; bias = bq; mode = 0; nw0 = nt * 64; }
    else if (nt == 16){ W = Wk; bias = bk; mode = 1; nw0 = 0; }
    else              { W = Wv; bias = bv; mode = 2; nw0 = 0; }

    const int tid = threadIdx.x;
    const int wave = tid >> 6, lane = tid & 63;
    const int l16 = lane & 15, quad = lane >> 4;
    const int m0 = blockIdx.y * 32;

    f32x4 acc[4];
    const f32x4 z = {0.f, 0.f, 0.f, 0.f};
#pragma unroll
    for (int ni = 0; ni < 4; ++ni) acc[ni] = z;

    for (int k0 = 0; k0 < K; k0 += 128) {
        STAGE_A32(As, A, m0, K)
        STAGE_B64(Bs, W, nw0, K)
        __syncthreads();

        short8 af[4], bfr[4][4];
        {
            int R = wave * 16 + l16;
#pragma unroll
            for (int kc = 0; kc < 4; ++kc)
                af[kc] = ld8(&As[R][((kc * 4 + quad) ^ (R & 15)) * 8]);
        }
#pragma unroll
        for (int ni = 0; ni < 4; ++ni) {
            int r = ni * 16 + l16;
#pragma unroll
            for (int kc = 0; kc < 4; ++kc)
                bfr[kc][ni] = ld8(&Bs[r][((kc * 4 + quad) ^ (r & 15)) * 8]);
        }
#pragma unroll
        for (int kc = 0; kc < 4; ++kc)
#pragma unroll
            for (int ni = 0; ni < 4; ++ni)
                acc[ni] = __builtin_amdgcn_mfma_f32_16x16x32_bf16(
                    af[kc], bfr[kc][ni], acc[ni], 0, 0, 0);
        __syncthreads();
    }

#pragma unroll
    for (int ni = 0; ni < 4; ++ni)
#pragma unroll
        for (int r = 0; r < 4; ++r) {
            int row = m0 + wave * 16 + quad * 4 + r;
            int col = ni * 16 + l16;
            float v = acc[ni][r] + bias[nw0 + col];
            if (mode == 0)
                qo[(size_t)row * 1024 + nt * 64 + col] = __float2bfloat16(v * 0.125f);
            else if (mode == 1)
                ko[(size_t)row * 64 + col] = __float2bfloat16(v);
            else
                vto[(size_t)col * M + row] = __float2bfloat16(v);
        }
}

// ---------------------------------------------------------------------------
// C[M,N] = A[M,K](bf16) @ W[N,K](bf16)^T + bias (fp32 out). 32x64, BK=128,
// 128 threads (2 waves).
__global__ void gemm_bt_mfma(const bf16* __restrict__ A, const bf16* __restrict__ W,
                             const float* __restrict__ bias, float* __restrict__ C,
                             int M, int N, int K) {
    __shared__ __align__(16) bf16 As[32][128];
    __shared__ __align__(16) bf16 Bs[64][128];
    const int tid = threadIdx.x;
    const int wave = tid >> 6, lane = tid & 63;
    const int l16 = lane & 15, quad = lane >> 4;
    const int m0 = blockIdx.y * 32, n0 = blockIdx.x * 64;

    f32x4 acc[4];
    const f32x4 z = {0.f, 0.f, 0.f, 0.f};
#pragma unroll
    for (int ni = 0; ni < 4; ++ni) acc[ni] = z;

    for (int k0 = 0; k0 < K; k0 += 128) {
        STAGE_A32(As, A, m0, K)
        STAGE_B64(Bs, W, n0, K)
        __syncthreads();

        short8 af[4], bfr[4][4];
        {
            int R = wave * 16 + l16;
#pragma unroll
            for (int kc = 0; kc < 4; ++kc)
                af[kc] = ld8(&As[R][((kc * 4 + quad) ^ (R & 15)) * 8]);
        }
#pragma unroll
        for (int ni = 0; ni < 4; ++ni) {
            int r = ni * 16 + l16;
#pragma unroll
            for (int kc = 0; kc < 4; ++kc)
                bfr[kc][ni] = ld8(&Bs[r][((kc * 4 + quad) ^ (r & 15)) * 8]);
        }
#pragma unroll
        for (int kc = 0; kc < 4; ++kc)
#pragma unroll
            for (int ni = 0; ni < 4; ++ni)
                acc[ni] = __builtin_amdgcn_mfma_f32_16x16x32_bf16(
                    af[kc], bfr[kc][ni], acc[ni], 0, 0, 0);
        __syncthreads();
    }

#pragma unroll
    for (int ni = 0; ni < 4; ++ni)
#pragma unroll
        for (int r = 0; r < 4; ++r) {
            int row = m0 + wave * 16 + quad * 4 + r;
            int col = n0 + ni * 16 + l16;
            C[(size_t)row * N + col] = acc[ni][r] + bias[col];
        }
}

// ---------------------------------------------------------------------------
// Flash causal MQA phase A — fixed-shift softmax, chunk = 8 k-tiles,
// single-buffered K/V (24.7 KB LDS, all 1280 blocks co-resident).
// 80 slots/head: s<32->(c0,i=s); <56->(c1,i=s-24); <72->(c2,i=s-40);
// else (c3,i=s-48). Blocks with s<8 are SINGLE-chunk (i<8): they hold the
// complete L -> write normalized attn directly, skipping the partial
// round-trip. Others write bf16 partial O + fp32 L.
__global__ void flash_mfma_kernel(const bf16* __restrict__ Q, const bf16* __restrict__ Kg,
                                  const bf16* __restrict__ VT,
                                  bf16* __restrict__ Opart, float* __restrict__ Lpart,
                                  bf16* __restrict__ attn, int S) {
    const int s = blockIdx.x;
    int i, c;
    if (s < 32)      { c = 0; i = s; }
    else if (s < 56) { c = 1; i = s - 24; }
    else if (s < 72) { c = 2; i = s - 40; }
    else             { c = 3; i = s - 48; }

    __shared__ __align__(16) bf16 Ks[64][64]; // 8 KB, XOR-swizzled
    __shared__ __align__(16) bf16 Vt[64][64]; // 8 KB, XOR-swizzled
    __shared__ bf16 Ps[4][16][68];            // 8.7 KB, stride 68 (0-conflict)

    const int h = blockIdx.y;
    const int q0 = i * 64;
    const int tid = threadIdx.x;
    const int wave = tid >> 6, lane = tid & 63;
    const int l16 = lane & 15, quad = lane >> 4;
    const int lr = lane >> 3, lsw = (lane & 7) ^ (lr & 7);
    const int qrow = q0 + wave * 16;

    short8 qf[2];
#pragma unroll
    for (int kc = 0; kc < 2; ++kc)
        qf[kc] = ld8(Q + (size_t)(qrow + l16) * 1024 + h * 64 + kc * 32 + quad * 8);

    // ones B-frag: column n=0 (l16==0 lanes) = 1.0 -> P row-sums via MFMA
    short8 onesf;
    {
        short o = (l16 == 0) ? (short)0x3F80 : (short)0;
        onesf[0]=o; onesf[1]=o; onesf[2]=o; onesf[3]=o;
        onesf[4]=o; onesf[5]=o; onesf[6]=o; onesf[7]=o;
    }

    f32x4 of[4];
    const f32x4 z = {0.f, 0.f, 0.f, 0.f};
#pragma unroll
    for (int dt = 0; dt < 4; ++dt) of[dt] = z;
    f32x4 lacc = z;

    const int jt0 = c * 8;
    const int jt1 = min(c * 8 + 8, i + 1);

    for (int jt = jt0; jt < jt1; ++jt) {
        const int j0 = jt * 64;
        // stage K/V tile (prior iter's readers finished at loop-end barrier)
#pragma unroll
        for (int u = 0; u < 2; ++u) {
            int t = wave * 2 + u;
            async_cp16(&Ks[t * 8][0], Kg + (size_t)(j0 + t * 8 + lr) * 64 + lsw * 8);
            async_cp16(&Vt[t * 8][0], VT + (size_t)(t * 8 + lr) * S + j0 + lsw * 8);
        }
        __syncthreads(); // staged data visible (drains vmcnt)

        // S = Q K^T (Q pre-scaled by 1/8)
        f32x4 sc[4];
#pragma unroll
        for (int nt = 0; nt < 4; ++nt) {
            int R = nt * 16 + l16;
            sc[nt] = __builtin_amdgcn_mfma_f32_16x16x32_bf16(
                qf[0], ld8(&Ks[R][(quad ^ (R & 7)) * 8]), z, 0, 0, 0);
            sc[nt] = __builtin_amdgcn_mfma_f32_16x16x32_bf16(
                qf[1], ld8(&Ks[R][((4 + quad) ^ (R & 7)) * 8]), sc[nt], 0, 0, 0);
        }
        bool need_mask = (j0 + 63 > qrow);
        if (need_mask) {
#pragma unroll
            for (int nt = 0; nt < 4; ++nt)
#pragma unroll
                for (int r = 0; r < 4; ++r)
                    if (j0 + nt * 16 + l16 > qrow + quad * 4 + r) sc[nt][r] = -1e30f;
        }

        // P = exp(S) (fixed shift; masked -> exp(-1e30) == 0), straight to LDS
#pragma unroll
        for (int nt = 0; nt < 4; ++nt)
#pragma unroll
            for (int r = 0; r < 4; ++r)
                Ps[wave][quad * 4 + r][nt * 16 + l16] = __float2bfloat16(__expf(sc[nt][r]));

        short8 pf[2];
        pf[0] = ld8(&Ps[wave][l16][quad * 8]);
        pf[1] = ld8(&Ps[wave][l16][32 + quad * 8]);

        // l += row-sums of P (ones-column MFMA; valid on l16==0 lanes)
        lacc = __builtin_amdgcn_mfma_f32_16x16x32_bf16(pf[0], onesf, lacc, 0, 0, 0);
        lacc = __builtin_amdgcn_mfma_f32_16x16x32_bf16(pf[1], onesf, lacc, 0, 0, 0);

        // O += P V (no rescale)
#pragma unroll
        for (int dt = 0; dt < 4; ++dt) {
            int R = dt * 16 + l16;
            of[dt] = __builtin_amdgcn_mfma_f32_16x16x32_bf16(
                pf[0], ld8(&Vt[R][(quad ^ (R & 7)) * 8]), of[dt], 0, 0, 0);
            of[dt] = __builtin_amdgcn_mfma_f32_16x16x32_bf16(
                pf[1], ld8(&Vt[R][((4 + quad) ^ (R & 7)) * 8]), of[dt], 0, 0, 0);
        }
        __syncthreads(); // all readers done before next iter overwrites Ks/Vt
    }

    if (s < 8) {
        // single-chunk q-tile: L complete -> write normalized attn directly.
        // lacc valid on l16==0 lane of each quad group; broadcast via shfl.
        float inv[4];
#pragma unroll
        for (int r = 0; r < 4; ++r)
            inv[r] = 1.f / __shfl(lacc[r], quad * 16);
#pragma unroll
        for (int dt = 0; dt < 4; ++dt)
#pragma unroll
            for (int r = 0; r < 4; ++r) {
                int row = q0 + wave * 16 + quad * 4 + r;
                attn[(size_t)row * 1024 + h * 64 + dt * 16 + l16] =
                    __float2bfloat16(of[dt][r] * inv[r]);
            }
        return;
    }

    // partials at slot (s, h): O as bf16 (64x64), L fp32
    bf16* Op = Opart + ((size_t)s * 16 + h) * 4096;
#pragma unroll
    for (int dt = 0; dt < 4; ++dt)
#pragma unroll
        for (int r = 0; r < 4; ++r) {
            int row = wave * 16 + quad * 4 + r;
            Op[row * 64 + dt * 16 + l16] = __float2bfloat16(of[dt][r]);
        }
    if (l16 == 0) {
        float* L = Lpart + ((size_t)s * 16 + h) * 64;
#pragma unroll
        for (int r = 0; r < 4; ++r)
            L[wave * 16 + quad * 4 + r] = lacc[r];
    }
}

// ---------------------------------------------------------------------------
// Merge 2..4 partials per (q-tile i>=8, head h): plain sums.
__global__ void flash_merge_kernel(const bf16* __restrict__ Opart,
                                   const float* __restrict__ Lpart,
                                   bf16* __restrict__ attn) {
    const int i = blockIdx.x + 8, h = blockIdx.y; // q-tiles 8..31
    const int nch = (i >> 3) + 1;                 // 2..4 chunks
    const int tid = threadIdx.x;
    const int row = tid >> 2, cg = (tid & 3) * 16;

    float L = 0.f;
    for (int cc = 0; cc < nch; ++cc) {
        int s = (cc == 0) ? i : (cc == 1) ? 24 + i : (cc == 2) ? 40 + i : 48 + i;
        L += Lpart[((size_t)s * 16 + h) * 64 + row];
    }
    float inv = 1.f / L;

    float o[16];
#pragma unroll
    for (int j = 0; j < 16; ++j) o[j] = 0.f;
    for (int cc = 0; cc < nch; ++cc) {
        int s = (cc == 0) ? i : (cc == 1) ? 24 + i : (cc == 2) ? 40 + i : 48 + i;
        const bf16* Op = Opart + ((size_t)s * 16 + h) * 4096 + row * 64 + cg;
#pragma unroll
        for (int j = 0; j < 16; ++j) o[j] += __bfloat162float(Op[j]);
    }
    bf16* dst = attn + (size_t)(i * 64 + row) * 1024 + h * 64 + cg;
#pragma unroll
    for (int j = 0; j < 16; ++j) dst[j] = __float2bfloat16(o[j] * inv);
}

// ---------------------------------------------------------------------------
extern "C" void kernel_launch(void* const* d_in, const int* in_sizes, int n_in,
                              void* d_out, int out_size, void* d_ws, size_t ws_size,
                              hipStream_t stream) {
    const int S = 2048, E = 1024, D = 64;

    const float* hs = (const float*)d_in[0];
    const float* Wq = (const float*)d_in[2];
    const float* bq = (const float*)d_in[3];
    const float* Wk = (const float*)d_in[4];
    const float* bk = (const float*)d_in[5];
    const float* Wv = (const float*)d_in[6];
    const float* bv = (const float*)d_in[7];
    const float* Wo = (const float*)d_in[8];
    const float* bo = (const float*)d_in[9];
    float* out = (float*)d_out;

    bf16* ws = (bf16*)d_ws;
    bf16* hsb = ws;                       // S*E
    bf16* wqb = hsb + (size_t)S * E;      // E*E
    bf16* wkb = wqb + (size_t)E * E;      // D*E
    bf16* wvb = wkb + (size_t)D * E;      // D*E
    bf16* wob = wvb + (size_t)D * E;      // E*E
    bf16* q = wob + (size_t)E * E;        // S*E (holds Q * 1/8)
    bf16* kbuf = q + (size_t)S * E;       // S*D
    bf16* vt = kbuf + (size_t)S * D;      // D*S (transposed)
    bf16* attn = vt + (size_t)S * D;      // S*E
    bf16* Opart = attn + (size_t)S * E;   // 1280 slots * 4096 bf16 (10.5 MB)
    float* Lpart = (float*)(Opart + (size_t)1280 * 4096); // 1280 * 64 f32

    cast_kernel<<<512, 256, 0, stream>>>(hs, hsb, S * E,
                                         Wq, wqb, E * E,
                                         Wk, wkb, D * E,
                                         Wv, wvb, D * E,
                                         Wo, wob, E * E);
    // fused Q/K/V projection (Q pre-scaled by 1/8): 32-row tiles, 2-wave blocks
    qkv_proj_kernel<<<dim3(18, S / 32), 128, 0, stream>>>(hsb, wqb, wkb, wvb,
                                                          bq, bk, bv,
                                                          q, kbuf, vt, S, E);
    // attention: chunk=8 k-split, single-buffered; i<8 writes attn directly
    flash_mfma_kernel<<<dim3(80, 16), 256, 0, stream>>>(q, kbuf, vt, Opart, Lpart, attn, S);
    flash_merge_kernel<<<dim3(24, 16), 256, 0, stream>>>(Opart, Lpart, attn);
    // output projection (fp32 out): 32-row tiles, 2-wave blocks
    gemm_bt_mfma<<<dim3(E / 64, S / 32), 128, 0, stream>>>(attn, wob, bo, out, S, E, E);
}

// Round 15
// 146.223 us; speedup vs baseline: 1.0279x; 1.0279x over previous
//
#include <hip/hip_runtime.h>
#include <hip/hip_bf16.h>

typedef __hip_bfloat16 bf16;
typedef __attribute__((ext_vector_type(8))) short short8;   // 8 bf16 = 4 VGPRs
typedef __attribute__((ext_vector_type(4))) float f32x4;    // MFMA C/D frag

__device__ __forceinline__ short8 ld8(const void* p) { return *(const short8*)p; }

// async global->LDS, 16B per lane: LDS dest = (wave-uniform) base + lane*16
__device__ __forceinline__ void async_cp16(bf16* lds, const bf16* g) {
    __builtin_amdgcn_global_load_lds(
        (const __attribute__((address_space(1))) unsigned int*)g,
        (__attribute__((address_space(3))) unsigned int*)lds, 16, 0, 0);
}

struct bf4 { bf16 a, b, c, d; };

// ---------------------------------------------------------------------------
__global__ void cast_kernel(const float* __restrict__ s0, bf16* __restrict__ d0, int n0_,
                            const float* __restrict__ s1, bf16* __restrict__ d1, int n1_,
                            const float* __restrict__ s2, bf16* __restrict__ d2, int n2_,
                            const float* __restrict__ s3, bf16* __restrict__ d3, int n3_,
                            const float* __restrict__ s4, bf16* __restrict__ d4, int n4_) {
    const float* srcs[5] = {s0, s1, s2, s3, s4};
    bf16* dsts[5] = {d0, d1, d2, d3, d4};
    int ns[5] = {n0_, n1_, n2_, n3_, n4_};
    int stride = gridDim.x * blockDim.x;
    int t0 = blockIdx.x * blockDim.x + threadIdx.x;
#pragma unroll
    for (int a = 0; a < 5; ++a) {
        const float4* src = (const float4*)srcs[a];
        bf4* dst = (bf4*)dsts[a];
        int n4 = ns[a] >> 2;
        for (int i = t0; i < n4; i += stride) {
            float4 v = src[i];
            bf4 o = {__float2bfloat16(v.x), __float2bfloat16(v.y),
                     __float2bfloat16(v.z), __float2bfloat16(v.w)};
            dst[i] = o;
        }
    }
}

// ---------------------------------------------------------------------------
// GEMM staging into XOR-16 swizzled [64][128] LDS tile (single-buffered,
// 8 K-iters at BK=128, 256 threads): inst t covers rows 4t..4t+3.
#define GEMM_STAGE(dst, src_base, row0, ldk)                                   \
    _Pragma("unroll")                                                          \
    for (int u = 0; u < 4; ++u) {                                              \
        int t = wave * 4 + u;                                                  \
        int row = t * 4 + (lane >> 4);                                         \
        int gsrc = (lane & 15) ^ (row & 15);                                   \
        async_cp16(&dst[t * 4][0], src_base + (size_t)(row0 + row) * ldk + k0 + gsrc * 8); \
    }

// ---------------------------------------------------------------------------
// Fused Q/K/V projection. A = hsb [M,K]. N-tiles: 0..15 -> Q (scaled 1/8),
// 16 -> K, 17 -> V (stored transposed). Tile 64(M)x64(N), BK=128, 256 thr.
__global__ void qkv_proj_kernel(const bf16* __restrict__ A,
                                const bf16* __restrict__ Wq, const bf16* __restrict__ Wk,
                                const bf16* __restrict__ Wv,
                                const float* __restrict__ bq, const float* __restrict__ bk,
                                const float* __restrict__ bv,
                                bf16* __restrict__ qo, bf16* __restrict__ ko,
                                bf16* __restrict__ vto, int M, int K) {
    __shared__ __align__(16) bf16 As[64][128]; // 16 KB
    __shared__ __align__(16) bf16 Bs[64][128]; // 16 KB
    const int nt = blockIdx.x;
    const bf16* W;
    const float* bias;
    int mode, nw0;
    if (nt < 16)      { W = Wq; bias = bq; mode = 0; nw0 = nt * 64; }
    else if (nt == 16){ W = Wk; bias = bk; mode = 1; nw0 = 0; }
    else              { W = Wv; bias = bv; mode = 2; nw0 = 0; }

    const int tid = threadIdx.x;
    const int wave = tid >> 6, lane = tid & 63;
    const int l16 = lane & 15, quad = lane >> 4;
    const int m0 = blockIdx.y * 64;

    f32x4 acc[4];
    const f32x4 z = {0.f, 0.f, 0.f, 0.f};
#pragma unroll
    for (int ni = 0; ni < 4; ++ni) acc[ni] = z;

    for (int k0 = 0; k0 < K; k0 += 128) {
        GEMM_STAGE(As, A, m0, K)
        GEMM_STAGE(Bs, W, nw0, K)
        __syncthreads();

        short8 af[4], bfr[4][4];
        {
            int R = wave * 16 + l16;
#pragma unroll
            for (int kc = 0; kc < 4; ++kc)
                af[kc] = ld8(&As[R][((kc * 4 + quad) ^ (R & 15)) * 8]);
        }
#pragma unroll
        for (int ni = 0; ni < 4; ++ni) {
            int r = ni * 16 + l16;
#pragma unroll
            for (int kc = 0; kc < 4; ++kc)
                bfr[kc][ni] = ld8(&Bs[r][((kc * 4 + quad) ^ (r & 15)) * 8]);
        }
#pragma unroll
        for (int kc = 0; kc < 4; ++kc)
#pragma unroll
            for (int ni = 0; ni < 4; ++ni)
                acc[ni] = __builtin_amdgcn_mfma_f32_16x16x32_bf16(
                    af[kc], bfr[kc][ni], acc[ni], 0, 0, 0);
        __syncthreads();
    }

#pragma unroll
    for (int ni = 0; ni < 4; ++ni)
#pragma unroll
        for (int r = 0; r < 4; ++r) {
            int row = m0 + wave * 16 + quad * 4 + r;
            int col = ni * 16 + l16;
            float v = acc[ni][r] + bias[nw0 + col];
            if (mode == 0)
                qo[(size_t)row * 1024 + nt * 64 + col] = __float2bfloat16(v * 0.125f);
            else if (mode == 1)
                ko[(size_t)row * 64 + col] = __float2bfloat16(v);
            else
                vto[(size_t)col * M + row] = __float2bfloat16(v);
        }
}

// ---------------------------------------------------------------------------
// C[M,N] = A[M,K](bf16) @ W[N,K](bf16)^T + bias (fp32 out). 64x64, BK=128.
__global__ void gemm_bt_mfma(const bf16* __restrict__ A, const bf16* __restrict__ W,
                             const float* __restrict__ bias, float* __restrict__ C,
                             int M, int N, int K) {
    __shared__ __align__(16) bf16 As[64][128];
    __shared__ __align__(16) bf16 Bs[64][128];
    const int tid = threadIdx.x;
    const int wave = tid >> 6, lane = tid & 63;
    const int l16 = lane & 15, quad = lane >> 4;
    const int m0 = blockIdx.y * 64, n0 = blockIdx.x * 64;

    f32x4 acc[4];
    const f32x4 z = {0.f, 0.f, 0.f, 0.f};
#pragma unroll
    for (int ni = 0; ni < 4; ++ni) acc[ni] = z;

    for (int k0 = 0; k0 < K; k0 += 128) {
        GEMM_STAGE(As, A, m0, K)
        GEMM_STAGE(Bs, W, n0, K)
        __syncthreads();

        short8 af[4], bfr[4][4];
        {
            int R = wave * 16 + l16;
#pragma unroll
            for (int kc = 0; kc < 4; ++kc)
                af[kc] = ld8(&As[R][((kc * 4 + quad) ^ (R & 15)) * 8]);
        }
#pragma unroll
        for (int ni = 0; ni < 4; ++ni) {
            int r = ni * 16 + l16;
#pragma unroll
            for (int kc = 0; kc < 4; ++kc)
                bfr[kc][ni] = ld8(&Bs[r][((kc * 4 + quad) ^ (r & 15)) * 8]);
        }
#pragma unroll
        for (int kc = 0; kc < 4; ++kc)
#pragma unroll
            for (int ni = 0; ni < 4; ++ni)
                acc[ni] = __builtin_amdgcn_mfma_f32_16x16x32_bf16(
                    af[kc], bfr[kc][ni], acc[ni], 0, 0, 0);
        __syncthreads();
    }

#pragma unroll
    for (int ni = 0; ni < 4; ++ni)
#pragma unroll
        for (int r = 0; r < 4; ++r) {
            int row = m0 + wave * 16 + quad * 4 + r;
            int col = n0 + ni * 16 + l16;
            C[(size_t)row * N + col] = acc[ni][r] + bias[col];
        }
}

// ---------------------------------------------------------------------------
// Flash causal MQA phase A — fixed-shift softmax, chunk = 8 k-tiles,
// single-buffered K/V (24.7 KB LDS, all 1280 blocks co-resident).
// 80 slots/head: s<32->(c0,i=s); <56->(c1,i=s-24); <72->(c2,i=s-40);
// else (c3,i=s-48). Blocks with s<8 are single-chunk (i<8): complete L ->
// write normalized attn directly. Others write bf16 partial O + fp32 L.
__global__ void flash_mfma_kernel(const bf16* __restrict__ Q, const bf16* __restrict__ Kg,
                                  const bf16* __restrict__ VT,
                                  bf16* __restrict__ Opart, float* __restrict__ Lpart,
                                  bf16* __restrict__ attn, int S) {
    const int s = blockIdx.x;
    int i, c;
    if (s < 32)      { c = 0; i = s; }
    else if (s < 56) { c = 1; i = s - 24; }
    else if (s < 72) { c = 2; i = s - 40; }
    else             { c = 3; i = s - 48; }

    __shared__ __align__(16) bf16 Ks[64][64]; // 8 KB, XOR-swizzled
    __shared__ __align__(16) bf16 Vt[64][64]; // 8 KB, XOR-swizzled
    __shared__ bf16 Ps[4][16][68];            // 8.7 KB, stride 68 (0-conflict)

    const int h = blockIdx.y;
    const int q0 = i * 64;
    const int tid = threadIdx.x;
    const int wave = tid >> 6, lane = tid & 63;
    const int l16 = lane & 15, quad = lane >> 4;
    const int lr = lane >> 3, lsw = (lane & 7) ^ (lr & 7);
    const int qrow = q0 + wave * 16;

    short8 qf[2];
#pragma unroll
    for (int kc = 0; kc < 2; ++kc)
        qf[kc] = ld8(Q + (size_t)(qrow + l16) * 1024 + h * 64 + kc * 32 + quad * 8);

    // ones B-frag: column n=0 (l16==0 lanes) = 1.0 -> P row-sums via MFMA
    short8 onesf;
    {
        short o = (l16 == 0) ? (short)0x3F80 : (short)0;
        onesf[0]=o; onesf[1]=o; onesf[2]=o; onesf[3]=o;
        onesf[4]=o; onesf[5]=o; onesf[6]=o; onesf[7]=o;
    }

    f32x4 of[4];
    const f32x4 z = {0.f, 0.f, 0.f, 0.f};
#pragma unroll
    for (int dt = 0; dt < 4; ++dt) of[dt] = z;
    f32x4 lacc = z;

    const int jt0 = c * 8;
    const int jt1 = min(c * 8 + 8, i + 1);

    for (int jt = jt0; jt < jt1; ++jt) {
        const int j0 = jt * 64;
        // stage K/V tile (prior iter's readers finished at loop-end barrier)
#pragma unroll
        for (int u = 0; u < 2; ++u) {
            int t = wave * 2 + u;
            async_cp16(&Ks[t * 8][0], Kg + (size_t)(j0 + t * 8 + lr) * 64 + lsw * 8);
            async_cp16(&Vt[t * 8][0], VT + (size_t)(t * 8 + lr) * S + j0 + lsw * 8);
        }
        __syncthreads(); // staged data visible (drains vmcnt)

        // S = Q K^T (Q pre-scaled by 1/8)
        f32x4 sc[4];
#pragma unroll
        for (int nt = 0; nt < 4; ++nt) {
            int R = nt * 16 + l16;
            sc[nt] = __builtin_amdgcn_mfma_f32_16x16x32_bf16(
                qf[0], ld8(&Ks[R][(quad ^ (R & 7)) * 8]), z, 0, 0, 0);
            sc[nt] = __builtin_amdgcn_mfma_f32_16x16x32_bf16(
                qf[1], ld8(&Ks[R][((4 + quad) ^ (R & 7)) * 8]), sc[nt], 0, 0, 0);
        }
        bool need_mask = (j0 + 63 > qrow);
        if (need_mask) {
#pragma unroll
            for (int nt = 0; nt < 4; ++nt)
#pragma unroll
                for (int r = 0; r < 4; ++r)
                    if (j0 + nt * 16 + l16 > qrow + quad * 4 + r) sc[nt][r] = -1e30f;
        }

        // P = exp(S) (fixed shift; masked -> exp(-1e30) == 0), straight to LDS
#pragma unroll
        for (int nt = 0; nt < 4; ++nt)
#pragma unroll
            for (int r = 0; r < 4; ++r)
                Ps[wave][quad * 4 + r][nt * 16 + l16] = __float2bfloat16(__expf(sc[nt][r]));

        short8 pf[2];
        pf[0] = ld8(&Ps[wave][l16][quad * 8]);
        pf[1] = ld8(&Ps[wave][l16][32 + quad * 8]);

        // l += row-sums of P (ones-column MFMA; valid on l16==0 lanes)
        lacc = __builtin_amdgcn_mfma_f32_16x16x32_bf16(pf[0], onesf, lacc, 0, 0, 0);
        lacc = __builtin_amdgcn_mfma_f32_16x16x32_bf16(pf[1], onesf, lacc, 0, 0, 0);

        // O += P V (no rescale)
#pragma unroll
        for (int dt = 0; dt < 4; ++dt) {
            int R = dt * 16 + l16;
            of[dt] = __builtin_amdgcn_mfma_f32_16x16x32_bf16(
                pf[0], ld8(&Vt[R][(quad ^ (R & 7)) * 8]), of[dt], 0, 0, 0);
            of[dt] = __builtin_amdgcn_mfma_f32_16x16x32_bf16(
                pf[1], ld8(&Vt[R][((4 + quad) ^ (R & 7)) * 8]), of[dt], 0, 0, 0);
        }
        __syncthreads(); // all readers done before next iter overwrites Ks/Vt
    }

    if (s < 8) {
        // single-chunk q-tile: L complete -> write normalized attn directly.
        float inv[4];
#pragma unroll
        for (int r = 0; r < 4; ++r)
            inv[r] = 1.f / __shfl(lacc[r], quad * 16);
#pragma unroll
        for (int dt = 0; dt < 4; ++dt)
#pragma unroll
            for (int r = 0; r < 4; ++r) {
                int row = q0 + wave * 16 + quad * 4 + r;
                attn[(size_t)row * 1024 + h * 64 + dt * 16 + l16] =
                    __float2bfloat16(of[dt][r] * inv[r]);
            }
        return;
    }

    // partials at slot (s, h): O as bf16 (64x64), L fp32
    bf16* Op = Opart + ((size_t)s * 16 + h) * 4096;
#pragma unroll
    for (int dt = 0; dt < 4; ++dt)
#pragma unroll
        for (int r = 0; r < 4; ++r) {
            int row = wave * 16 + quad * 4 + r;
            Op[row * 64 + dt * 16 + l16] = __float2bfloat16(of[dt][r]);
        }
    if (l16 == 0) {
        float* L = Lpart + ((size_t)s * 16 + h) * 64;
#pragma unroll
        for (int r = 0; r < 4; ++r)
            L[wave * 16 + quad * 4 + r] = lacc[r];
    }
}

// ---------------------------------------------------------------------------
// Merge 2..4 partials per (q-tile i>=8, head h): plain sums.
__global__ void flash_merge_kernel(const bf16* __restrict__ Opart,
                                   const float* __restrict__ Lpart,
                                   bf16* __restrict__ attn) {
    const int i = blockIdx.x + 8, h = blockIdx.y; // q-tiles 8..31
    const int nch = (i >> 3) + 1;                 // 2..4 chunks
    const int tid = threadIdx.x;
    const int row = tid >> 2, cg = (tid & 3) * 16;

    float L = 0.f;
    for (int cc = 0; cc < nch; ++cc) {
        int s = (cc == 0) ? i : (cc == 1) ? 24 + i : (cc == 2) ? 40 + i : 48 + i;
        L += Lpart[((size_t)s * 16 + h) * 64 + row];
    }
    float inv = 1.f / L;

    float o[16];
#pragma unroll
    for (int j = 0; j < 16; ++j) o[j] = 0.f;
    for (int cc = 0; cc < nch; ++cc) {
        int s = (cc == 0) ? i : (cc == 1) ? 24 + i : (cc == 2) ? 40 + i : 48 + i;
        const bf16* Op = Opart + ((size_t)s * 16 + h) * 4096 + row * 64 + cg;
#pragma unroll
        for (int j = 0; j < 16; ++j) o[j] += __bfloat162float(Op[j]);
    }
    bf16* dst = attn + (size_t)(i * 64 + row) * 1024 + h * 64 + cg;
#pragma unroll
    for (int j = 0; j < 16; ++j) dst[j] = __float2bfloat16(o[j] * inv);
}

// ---------------------------------------------------------------------------
extern "C" void kernel_launch(void* const* d_in, const int* in_sizes, int n_in,
                              void* d_out, int out_size, void* d_ws, size_t ws_size,
                              hipStream_t stream) {
    const int S = 2048, E = 1024, D = 64;

    const float* hs = (const float*)d_in[0];
    const float* Wq = (const float*)d_in[2];
    const float* bq = (const float*)d_in[3];
    const float* Wk = (const float*)d_in[4];
    const float* bk = (const float*)d_in[5];
    const float* Wv = (const float*)d_in[6];
    const float* bv = (const float*)d_in[7];
    const float* Wo = (const float*)d_in[8];
    const float* bo = (const float*)d_in[9];
    float* out = (float*)d_out;

    bf16* ws = (bf16*)d_ws;
    bf16* hsb = ws;                       // S*E
    bf16* wqb = hsb + (size_t)S * E;      // E*E
    bf16* wkb = wqb + (size_t)E * E;      // D*E
    bf16* wvb = wkb + (size_t)D * E;      // D*E
    bf16* wob = wvb + (size_t)D * E;      // E*E
    bf16* q = wob + (size_t)E * E;        // S*E (holds Q * 1/8)
    bf16* kbuf = q + (size_t)S * E;       // S*D
    bf16* vt = kbuf + (size_t)S * D;      // D*S (transposed)
    bf16* attn = vt + (size_t)S * D;      // S*E
    bf16* Opart = attn + (size_t)S * E;   // 1280 slots * 4096 bf16 (10.5 MB)
    float* Lpart = (float*)(Opart + (size_t)1280 * 4096); // 1280 * 64 f32

    cast_kernel<<<512, 256, 0, stream>>>(hs, hsb, S * E,
                                         Wq, wqb, E * E,
                                         Wk, wkb, D * E,
                                         Wv, wvb, D * E,
                                         Wo, wob, E * E);
    // fused Q/K/V projection (Q pre-scaled by 1/8): 64-row tiles, BK=128
    qkv_proj_kernel<<<dim3(18, S / 64), 256, 0, stream>>>(hsb, wqb, wkb, wvb,
                                                          bq, bk, bv,
                                                          q, kbuf, vt, S, E);
    // attention: chunk=8 k-split, single-buffered; i<8 writes attn directly
    flash_mfma_kernel<<<dim3(80, 16), 256, 0, stream>>>(q, kbuf, vt, Opart, Lpart, attn, S);
    flash_merge_kernel<<<dim3(24, 16), 256, 0, stream>>>(Opart, Lpart, attn);
    // output projection (fp32 out): 64-row tiles, BK=128
    gemm_bt_mfma<<<dim3(E / 64, S / 64), 256, 0, stream>>>(attn, wob, bo, out, S, E, E);
}